// Round 6
// baseline (1124.083 us; speedup 1.0000x reference)
//
#include <hip/hip_runtime.h>
#include <math.h>

#define N_NODES 50000
#define E_EDGES 250000
#define ETOT    300000   // E + N self loops
#define B_G     64
#define NHEAD1  4
#define C1      64
#define D1      256      // NHEAD1*C1
#define C2      64
#define NEG     0.2f

__device__ __forceinline__ float leaky(float v){ return v >= 0.f ? v : NEG * v; }
__device__ __forceinline__ float elu_f(float v){ return v > 0.f ? v : expm1f(v); }

// monotonic float<->uint encoding for atomicMax on floats
__device__ __forceinline__ unsigned fenc(float f){
    unsigned u = __float_as_uint(f);
    return (u & 0x80000000u) ? ~u : (u | 0x80000000u);
}
__device__ __forceinline__ float fdec(unsigned u){
    u = (u & 0x80000000u) ? (u ^ 0x80000000u) : ~u;
    return __uint_as_float(u);
}

// ---------------- init ----------------
__global__ void k_init(int* deg, float* pool_sum, unsigned* pool_max, int* pool_cnt){
    int i = blockIdx.x * 256 + threadIdx.x;
    if (i < N_NODES) deg[i] = 0;
    if (i < B_G * C2){ pool_sum[i] = 0.f; pool_max[i] = fenc(-INFINITY); }
    if (i < B_G) pool_cnt[i] = 0;
}

// ---------------- conv1 linear (K=5) ----------------
__global__ void k_lin1(const float* __restrict__ x,
                       const float* __restrict__ Wl, const float* __restrict__ bl,
                       const float* __restrict__ Wr, const float* __restrict__ br,
                       float* __restrict__ xl, float* __restrict__ xr){
    int n = blockIdx.x;          // node
    int o = threadIdx.x;         // 0..255
    float x0 = x[n*5+0], x1 = x[n*5+1], x2 = x[n*5+2], x3 = x[n*5+3], x4 = x[n*5+4];
    float vl = bl[o] + x0*Wl[o] + x1*Wl[256+o] + x2*Wl[512+o] + x3*Wl[768+o] + x4*Wl[1024+o];
    float vr = br[o] + x0*Wr[o] + x1*Wr[256+o] + x2*Wr[512+o] + x3*Wr[768+o] + x4*Wr[1024+o];
    int idx = n * D1 + o;
    xl[idx] = vl;
    xr[idx] = vr;
}

// ---------------- CSR build ----------------
__global__ void k_deg(const int* __restrict__ ei, int* __restrict__ deg){
    int e = blockIdx.x * 256 + threadIdx.x;
    if (e >= ETOT) return;
    int dst = (e < E_EDGES) ? ei[E_EDGES + e] : (e - E_EDGES);
    atomicAdd(&deg[dst], 1);
}

__global__ void k_scan(const int* __restrict__ deg, int* __restrict__ row_ptr, int* __restrict__ cursor){
    __shared__ int part[1024];
    int t = threadIdx.x;
    const int CH = (N_NODES + 1023) / 1024;
    int base = t * CH;
    int s = 0;
    for (int k = 0; k < CH; k++){ int i = base + k; if (i < N_NODES) s += deg[i]; }
    part[t] = s;
    __syncthreads();
    for (int off = 1; off < 1024; off <<= 1){
        int v = (t >= off) ? part[t - off] : 0;
        __syncthreads();
        part[t] += v;
        __syncthreads();
    }
    int run = (t == 0) ? 0 : part[t - 1];
    for (int k = 0; k < CH; k++){
        int i = base + k;
        if (i < N_NODES){ row_ptr[i] = run; cursor[i] = run; run += deg[i]; }
    }
    if (t == 1023) row_ptr[N_NODES] = part[1023];
}

__global__ void k_fill(const int* __restrict__ ei, int* __restrict__ cursor,
                       int* __restrict__ csr_src, int* __restrict__ csr_eid){
    int e = blockIdx.x * 256 + threadIdx.x;
    if (e >= ETOT) return;
    int src, dst;
    if (e < E_EDGES){ src = ei[e]; dst = ei[E_EDGES + e]; }
    else            { src = dst = e - E_EDGES; }
    int pos = atomicAdd(&cursor[dst], 1);
    csr_src[pos] = src;
    csr_eid[pos] = e;
}

// ---------------- conv1 attention logits ----------------
__global__ void k_att1(const int* __restrict__ ei,
                       const float* __restrict__ xl, const float* __restrict__ xr,
                       const float* __restrict__ att, float* __restrict__ e1){
    int idx = blockIdx.x * 256 + threadIdx.x;
    if (idx >= ETOT * NHEAD1) return;
    int e = idx >> 2, h = idx & 3;
    int src, dst;
    if (e < E_EDGES){ src = ei[e]; dst = ei[E_EDGES + e]; }
    else            { src = dst = e - E_EDGES; }
    const float4* pl = (const float4*)(xl + (size_t)src * D1 + h * C1);
    const float4* pr = (const float4*)(xr + (size_t)dst * D1 + h * C1);
    const float4* pa = (const float4*)(att + h * C1);
    float acc = 0.f;
    #pragma unroll
    for (int k = 0; k < 16; k++){
        float4 a = pl[k], b = pr[k], w = pa[k];
        acc += leaky(a.x + b.x) * w.x + leaky(a.y + b.y) * w.y
             + leaky(a.z + b.z) * w.z + leaky(a.w + b.w) * w.w;
    }
    e1[idx] = acc;
}

// ---------------- conv1 aggregation (softmax + gather + ELU) ----------------
__global__ void k_agg1(const int* __restrict__ row_ptr, const int* __restrict__ csr_src,
                       const int* __restrict__ csr_eid, const float* __restrict__ e1,
                       const float* __restrict__ xl, const float* __restrict__ bias,
                       float* __restrict__ hout){
    int nd = blockIdx.x;
    int t = threadIdx.x;          // channel 0..255
    int h = t >> 6;
    int beg = row_ptr[nd], end = row_ptr[nd + 1];
    float m = -INFINITY;
    for (int k = beg; k < end; k++){
        m = fmaxf(m, e1[csr_eid[k] * 4 + h]);
    }
    float s = 0.f, acc = 0.f;
    for (int k = beg; k < end; k++){
        float w = __expf(e1[csr_eid[k] * 4 + h] - m);
        s += w;
        acc += w * xl[(size_t)csr_src[k] * D1 + t];
    }
    hout[(size_t)nd * D1 + t] = elu_f(acc / s + bias[t]);
}

// ---------------- conv2 linear (K=256) ----------------
__global__ void k_lin2(const float* __restrict__ h1,
                       const float* __restrict__ Wl, const float* __restrict__ bl,
                       const float* __restrict__ Wr, const float* __restrict__ br,
                       float* __restrict__ xl2, float* __restrict__ xr2){
    __shared__ float row[D1];
    int nd = blockIdx.x, t = threadIdx.x;   // 64 threads
    for (int k = t; k < D1; k += 64) row[k] = h1[(size_t)nd * D1 + k];
    __syncthreads();
    float al = bl[t], ar = br[t];
    for (int k = 0; k < D1; k++){
        float hv = row[k];
        al += hv * Wl[k * 64 + t];
        ar += hv * Wr[k * 64 + t];
    }
    xl2[nd * 64 + t] = al;
    xr2[nd * 64 + t] = ar;
}

// ---------------- conv2 attention logits (H=1) ----------------
__global__ void k_att2(const int* __restrict__ ei,
                       const float* __restrict__ xl2, const float* __restrict__ xr2,
                       const float* __restrict__ att, float* __restrict__ e2){
    int e = blockIdx.x * 256 + threadIdx.x;
    if (e >= ETOT) return;
    int src, dst;
    if (e < E_EDGES){ src = ei[e]; dst = ei[E_EDGES + e]; }
    else            { src = dst = e - E_EDGES; }
    const float4* pl = (const float4*)(xl2 + (size_t)src * C2);
    const float4* pr = (const float4*)(xr2 + (size_t)dst * C2);
    const float4* pa = (const float4*)att;
    float acc = 0.f;
    #pragma unroll
    for (int k = 0; k < 16; k++){
        float4 a = pl[k], b = pr[k], w = pa[k];
        acc += leaky(a.x + b.x) * w.x + leaky(a.y + b.y) * w.y
             + leaky(a.z + b.z) * w.z + leaky(a.w + b.w) * w.w;
    }
    e2[e] = acc;
}

// ---------------- conv2 aggregation ----------------
__global__ void k_agg2(const int* __restrict__ row_ptr, const int* __restrict__ csr_src,
                       const int* __restrict__ csr_eid, const float* __restrict__ e2,
                       const float* __restrict__ xl2, const float* __restrict__ bias,
                       float* __restrict__ hout){
    int nd = blockIdx.x;
    int t = threadIdx.x;          // 0..63
    int beg = row_ptr[nd], end = row_ptr[nd + 1];
    float m = -INFINITY;
    for (int k = beg; k < end; k++) m = fmaxf(m, e2[csr_eid[k]]);
    float s = 0.f, acc = 0.f;
    for (int k = beg; k < end; k++){
        float w = __expf(e2[csr_eid[k]] - m);
        s += w;
        acc += w * xl2[(size_t)csr_src[k] * C2 + t];
    }
    hout[nd * C2 + t] = elu_f(acc / s + bias[t]);
}

// ---------------- pooling ----------------
__global__ void k_pool(const float* __restrict__ h2, const int* __restrict__ batch,
                       float* __restrict__ pool_sum, unsigned* __restrict__ pool_max,
                       int* __restrict__ pool_cnt){
    int nd = blockIdx.x, c = threadIdx.x;   // 64 threads
    int b = batch[nd];
    float v = h2[nd * C2 + c];
    atomicAdd(&pool_sum[b * C2 + c], v);
    atomicMax(&pool_max[b * C2 + c], fenc(v));
    if (c == 0) atomicAdd(&pool_cnt[b], 1);
}

// ---------------- final linear [B,192]@[192,2] ----------------
__global__ void k_final(const float* __restrict__ pool_sum, const unsigned* __restrict__ pool_max,
                        const int* __restrict__ pool_cnt,
                        const float* __restrict__ Wlin, const float* __restrict__ blin,
                        float* __restrict__ out){
    int t = threadIdx.x;
    if (t >= B_G * 2) return;
    int b = t >> 1, o = t & 1;
    float cnt = fmaxf((float)pool_cnt[b], 1.f);
    float acc = blin[o];
    for (int j = 0; j < C2; j++){
        float sm = pool_sum[b * C2 + j];
        float mx = fdec(pool_max[b * C2 + j]);
        acc += (sm / cnt) * Wlin[j * 2 + o];
        acc += mx * Wlin[(C2 + j) * 2 + o];
        acc += sm * Wlin[(2 * C2 + j) * 2 + o];
    }
    out[b * 2 + o] = acc;
}

extern "C" void kernel_launch(void* const* d_in, const int* in_sizes, int n_in,
                              void* d_out, int out_size, void* d_ws, size_t ws_size,
                              hipStream_t stream) {
    const float* x     = (const float*)d_in[0];
    const int*   ei    = (const int*)d_in[1];
    const int*   batch = (const int*)d_in[2];
    const float* Wl1   = (const float*)d_in[3];
    const float* bl1   = (const float*)d_in[4];
    const float* Wr1   = (const float*)d_in[5];
    const float* br1   = (const float*)d_in[6];
    const float* att1  = (const float*)d_in[7];
    const float* bias1 = (const float*)d_in[8];
    const float* Wl2   = (const float*)d_in[9];
    const float* bl2   = (const float*)d_in[10];
    const float* Wr2   = (const float*)d_in[11];
    const float* br2   = (const float*)d_in[12];
    const float* att2  = (const float*)d_in[13];
    const float* bias2 = (const float*)d_in[14];
    const float* Wlin  = (const float*)d_in[15];
    const float* blin  = (const float*)d_in[16];
    float* out = (float*)d_out;

    char* w = (char*)d_ws;
    float* bufA = (float*)w;  w += (size_t)N_NODES * D1 * 4;   // xl1 ; later xl2|xr2
    float* bufB = (float*)w;  w += (size_t)N_NODES * D1 * 4;   // xr1 -> h1 ; later h2
    float* e1   = (float*)w;  w += (size_t)ETOT * NHEAD1 * 4;
    float* e2   = (float*)w;  w += (size_t)ETOT * 4;
    int* deg    = (int*)w;    w += (size_t)N_NODES * 4;
    int* row_ptr= (int*)w;    w += (size_t)(N_NODES + 1) * 4;
    int* cursor = (int*)w;    w += (size_t)N_NODES * 4;
    int* csr_src= (int*)w;    w += (size_t)ETOT * 4;
    int* csr_eid= (int*)w;    w += (size_t)ETOT * 4;
    float*    pool_sum = (float*)w;    w += (size_t)B_G * C2 * 4;
    unsigned* pool_max = (unsigned*)w; w += (size_t)B_G * C2 * 4;
    int*      pool_cnt = (int*)w;      w += (size_t)B_G * 4;

    float* xl1 = bufA;
    float* xr1 = bufB;
    float* h1  = bufB;                              // overwrites xr1 (dead after k_att1)
    float* xl2 = bufA;                              // overwrites xl1 (dead after k_agg1)
    float* xr2 = bufA + (size_t)N_NODES * C2;
    float* h2  = bufB;                              // overwrites h1 (dead after k_lin2)

    // init accumulators / counters
    k_init<<<(N_NODES + 255) / 256, 256, 0, stream>>>(deg, pool_sum, pool_max, pool_cnt);
    // conv1 linear
    k_lin1<<<N_NODES, 256, 0, stream>>>(x, Wl1, bl1, Wr1, br1, xl1, xr1);
    // CSR build (shared by both convs)
    k_deg<<<(ETOT + 255) / 256, 256, 0, stream>>>(ei, deg);
    k_scan<<<1, 1024, 0, stream>>>(deg, row_ptr, cursor);
    k_fill<<<(ETOT + 255) / 256, 256, 0, stream>>>(ei, cursor, csr_src, csr_eid);
    // conv1 attention + aggregation
    k_att1<<<(ETOT * NHEAD1 + 255) / 256, 256, 0, stream>>>(ei, xl1, xr1, att1, e1);
    k_agg1<<<N_NODES, 256, 0, stream>>>(row_ptr, csr_src, csr_eid, e1, xl1, bias1, h1);
    // conv2
    k_lin2<<<N_NODES, 64, 0, stream>>>(h1, Wl2, bl2, Wr2, br2, xl2, xr2);
    k_att2<<<(ETOT + 255) / 256, 256, 0, stream>>>(ei, xl2, xr2, att2, e2);
    k_agg2<<<N_NODES, 64, 0, stream>>>(row_ptr, csr_src, csr_eid, e2, xl2, bias2, h2);
    // pooling + head
    k_pool<<<N_NODES, 64, 0, stream>>>(h2, batch, pool_sum, pool_max, pool_cnt);
    k_final<<<1, 128, 0, stream>>>(pool_sum, pool_max, pool_cnt, Wlin, blin, out);
}

// Round 9
// 742.601 us; speedup vs baseline: 1.5137x; 1.5137x over previous
//
#include <hip/hip_runtime.h>
#include <math.h>

#define N_NODES 50000
#define E_EDGES 250000
#define ETOT    300000   // E + N self loops
#define B_G     64
#define NHEAD1  4
#define C1      64
#define D1      256      // NHEAD1*C1
#define C2      64
#define NEG     0.2f

__device__ __forceinline__ float leaky(float v){ return v >= 0.f ? v : NEG * v; }
__device__ __forceinline__ float elu_f(float v){ return v > 0.f ? v : expm1f(v); }

// ---------------- init ----------------
__global__ void k_init(int* deg){
    int i = blockIdx.x * 256 + threadIdx.x;
    if (i < N_NODES) deg[i] = 0;
}

// ---------------- conv1 linear (K=5) ----------------
__global__ void k_lin1(const float* __restrict__ x,
                       const float* __restrict__ Wl, const float* __restrict__ bl,
                       const float* __restrict__ Wr, const float* __restrict__ br,
                       float* __restrict__ xl, float* __restrict__ xr){
    int n = blockIdx.x;          // node
    int o = threadIdx.x;         // 0..255
    float x0 = x[n*5+0], x1 = x[n*5+1], x2 = x[n*5+2], x3 = x[n*5+3], x4 = x[n*5+4];
    float vl = bl[o] + x0*Wl[o] + x1*Wl[256+o] + x2*Wl[512+o] + x3*Wl[768+o] + x4*Wl[1024+o];
    float vr = br[o] + x0*Wr[o] + x1*Wr[256+o] + x2*Wr[512+o] + x3*Wr[768+o] + x4*Wr[1024+o];
    int idx = n * D1 + o;
    xl[idx] = vl;
    xr[idx] = vr;
}

// ---------------- CSR build ----------------
__global__ void k_deg(const int* __restrict__ ei, int* __restrict__ deg){
    int e = blockIdx.x * 256 + threadIdx.x;
    if (e >= ETOT) return;
    int dst = (e < E_EDGES) ? ei[E_EDGES + e] : (e - E_EDGES);
    atomicAdd(&deg[dst], 1);
}

__global__ void k_scan(const int* __restrict__ deg, int* __restrict__ row_ptr, int* __restrict__ cursor){
    __shared__ int part[1024];
    int t = threadIdx.x;
    const int CH = (N_NODES + 1023) / 1024;
    int base = t * CH;
    int s = 0;
    for (int k = 0; k < CH; k++){ int i = base + k; if (i < N_NODES) s += deg[i]; }
    part[t] = s;
    __syncthreads();
    for (int off = 1; off < 1024; off <<= 1){
        int v = (t >= off) ? part[t - off] : 0;
        __syncthreads();
        part[t] += v;
        __syncthreads();
    }
    int run = (t == 0) ? 0 : part[t - 1];
    for (int k = 0; k < CH; k++){
        int i = base + k;
        if (i < N_NODES){ row_ptr[i] = run; cursor[i] = run; run += deg[i]; }
    }
    if (t == 1023) row_ptr[N_NODES] = part[1023];
}

__global__ void k_fill(const int* __restrict__ ei, int* __restrict__ cursor,
                       int* __restrict__ csr_src, int* __restrict__ csr_eid){
    int e = blockIdx.x * 256 + threadIdx.x;
    if (e >= ETOT) return;
    int src, dst;
    if (e < E_EDGES){ src = ei[e]; dst = ei[E_EDGES + e]; }
    else            { src = dst = e - E_EDGES; }
    int pos = atomicAdd(&cursor[dst], 1);
    csr_src[pos] = src;
    csr_eid[pos] = e;
}

// ---------------- conv1 attention logits ----------------
__global__ void k_att1(const int* __restrict__ ei,
                       const float* __restrict__ xl, const float* __restrict__ xr,
                       const float* __restrict__ att, float* __restrict__ e1){
    int idx = blockIdx.x * 256 + threadIdx.x;
    if (idx >= ETOT * NHEAD1) return;
    int e = idx >> 2, h = idx & 3;
    int src, dst;
    if (e < E_EDGES){ src = ei[e]; dst = ei[E_EDGES + e]; }
    else            { src = dst = e - E_EDGES; }
    const float4* pl = (const float4*)(xl + (size_t)src * D1 + h * C1);
    const float4* pr = (const float4*)(xr + (size_t)dst * D1 + h * C1);
    const float4* pa = (const float4*)(att + h * C1);
    float acc = 0.f;
    #pragma unroll
    for (int k = 0; k < 16; k++){
        float4 a = pl[k], b = pr[k], w = pa[k];
        acc += leaky(a.x + b.x) * w.x + leaky(a.y + b.y) * w.y
             + leaky(a.z + b.z) * w.z + leaky(a.w + b.w) * w.w;
    }
    e1[idx] = acc;
}

// ---------------- conv1 aggregation (softmax + gather + ELU) ----------------
__global__ void k_agg1(const int* __restrict__ row_ptr, const int* __restrict__ csr_src,
                       const int* __restrict__ csr_eid, const float* __restrict__ e1,
                       const float* __restrict__ xl, const float* __restrict__ bias,
                       float* __restrict__ hout){
    int nd = blockIdx.x;
    int t = threadIdx.x;          // channel 0..255
    int h = t >> 6;
    int beg = row_ptr[nd], end = row_ptr[nd + 1];
    float m = -INFINITY;
    for (int k = beg; k < end; k++){
        m = fmaxf(m, e1[csr_eid[k] * 4 + h]);
    }
    float s = 0.f, acc = 0.f;
    for (int k = beg; k < end; k++){
        float w = __expf(e1[csr_eid[k] * 4 + h] - m);
        s += w;
        acc += w * xl[(size_t)csr_src[k] * D1 + t];
    }
    hout[(size_t)nd * D1 + t] = elu_f(acc / s + bias[t]);
}

// ---------------- conv2 linear (K=256), 16 nodes per block ----------------
#define LIN2_NB 16
__global__ void k_lin2(const float* __restrict__ h1,
                       const float* __restrict__ Wl, const float* __restrict__ bl,
                       const float* __restrict__ Wr, const float* __restrict__ br,
                       float* __restrict__ xl2, float* __restrict__ xr2){
    __shared__ float rows[LIN2_NB * D1];   // 16 KB, same layout as h1 slab
    int base = blockIdx.x * LIN2_NB;       // first node of this block
    int t = threadIdx.x;                   // 0..255
    // stage 16 rows (16*256 floats = 1024 float4)
    const float4* src4 = (const float4*)(h1 + (size_t)base * D1);
    float4* dst4 = (float4*)rows;
    for (int i = t; i < LIN2_NB * D1 / 4; i += 256) dst4[i] = src4[i];
    __syncthreads();

    int c     = t & 63;         // output channel
    int which = (t >> 6) & 1;   // 0 = l, 1 = r
    int ng    = t >> 7;         // node parity 0..1 -> handles nodes ng, ng+2, ...
    const float* W = which ? Wr : Wl;
    float bias = which ? br[c] : bl[c];
    float acc[8];
    #pragma unroll
    for (int j = 0; j < 8; j++) acc[j] = bias;

    for (int k = 0; k < D1; k++){
        float w = W[k * 64 + c];
        #pragma unroll
        for (int j = 0; j < 8; j++)
            acc[j] += rows[(ng + j * 2) * D1 + k] * w;   // LDS broadcast per wave
    }
    float* dst = which ? xr2 : xl2;
    #pragma unroll
    for (int j = 0; j < 8; j++){
        int node = base + ng + j * 2;
        dst[(size_t)node * 64 + c] = acc[j];
    }
}

// ---------------- conv2 attention logits (H=1) ----------------
__global__ void k_att2(const int* __restrict__ ei,
                       const float* __restrict__ xl2, const float* __restrict__ xr2,
                       const float* __restrict__ att, float* __restrict__ e2){
    int e = blockIdx.x * 256 + threadIdx.x;
    if (e >= ETOT) return;
    int src, dst;
    if (e < E_EDGES){ src = ei[e]; dst = ei[E_EDGES + e]; }
    else            { src = dst = e - E_EDGES; }
    const float4* pl = (const float4*)(xl2 + (size_t)src * C2);
    const float4* pr = (const float4*)(xr2 + (size_t)dst * C2);
    const float4* pa = (const float4*)att;
    float acc = 0.f;
    #pragma unroll
    for (int k = 0; k < 16; k++){
        float4 a = pl[k], b = pr[k], w = pa[k];
        acc += leaky(a.x + b.x) * w.x + leaky(a.y + b.y) * w.y
             + leaky(a.z + b.z) * w.z + leaky(a.w + b.w) * w.w;
    }
    e2[e] = acc;
}

// ---------------- conv2 aggregation ----------------
__global__ void k_agg2(const int* __restrict__ row_ptr, const int* __restrict__ csr_src,
                       const int* __restrict__ csr_eid, const float* __restrict__ e2,
                       const float* __restrict__ xl2, const float* __restrict__ bias,
                       float* __restrict__ hout){
    int nd = blockIdx.x;
    int t = threadIdx.x;          // 0..63
    int beg = row_ptr[nd], end = row_ptr[nd + 1];
    float m = -INFINITY;
    for (int k = beg; k < end; k++) m = fmaxf(m, e2[csr_eid[k]]);
    float s = 0.f, acc = 0.f;
    for (int k = beg; k < end; k++){
        float w = __expf(e2[csr_eid[k]] - m);
        s += w;
        acc += w * xl2[(size_t)csr_src[k] * C2 + t];
    }
    hout[nd * C2 + t] = elu_f(acc / s + bias[t]);
}

// ---------------- pooling: one block per graph, zero atomics ----------------
// batch is sorted, so graph b's nodes are a contiguous range found by binary search.
__device__ __forceinline__ int lower_bound_batch(const int* __restrict__ batch, int val){
    int lo = 0, hi = N_NODES;
    while (lo < hi){ int mid = (lo + hi) >> 1; if (batch[mid] < val) lo = mid + 1; else hi = mid; }
    return lo;
}

__global__ void k_pool(const float* __restrict__ h2, const int* __restrict__ batch,
                       float* __restrict__ pool_sum, float* __restrict__ pool_max,
                       int* __restrict__ pool_cnt){
    __shared__ float ssum[256], smax[256];
    int b = blockIdx.x;            // graph id
    int t = threadIdx.x;           // 0..255
    int lo = lower_bound_batch(batch, b);
    int hi = lower_bound_batch(batch, b + 1);
    int c = t & 63;                // channel
    int j = t >> 6;                // node slice 0..3
    float s = 0.f, mx = -INFINITY;
    for (int nd = lo + j; nd < hi; nd += 4){
        float v = h2[(size_t)nd * C2 + c];   // 256B coalesced per wave
        s += v;
        mx = fmaxf(mx, v);
    }
    ssum[t] = s; smax[t] = mx;
    __syncthreads();
    if (t < 128){ ssum[t] += ssum[t + 128]; smax[t] = fmaxf(smax[t], smax[t + 128]); }
    __syncthreads();
    if (t < 64){
        pool_sum[b * C2 + t] = ssum[t] + ssum[t + 64];
        pool_max[b * C2 + t] = fmaxf(smax[t], smax[t + 64]);
    }
    if (t == 0) pool_cnt[b] = hi - lo;
}

// ---------------- final linear [B,192]@[192,2] ----------------
__global__ void k_final(const float* __restrict__ pool_sum, const float* __restrict__ pool_max,
                        const int* __restrict__ pool_cnt,
                        const float* __restrict__ Wlin, const float* __restrict__ blin,
                        float* __restrict__ out){
    int t = threadIdx.x;
    if (t >= B_G * 2) return;
    int b = t >> 1, o = t & 1;
    float cnt = fmaxf((float)pool_cnt[b], 1.f);
    float acc = blin[o];
    for (int j = 0; j < C2; j++){
        float sm = pool_sum[b * C2 + j];
        float mx = pool_max[b * C2 + j];
        acc += (sm / cnt) * Wlin[j * 2 + o];
        acc += mx * Wlin[(C2 + j) * 2 + o];
        acc += sm * Wlin[(2 * C2 + j) * 2 + o];
    }
    out[b * 2 + o] = acc;
}

extern "C" void kernel_launch(void* const* d_in, const int* in_sizes, int n_in,
                              void* d_out, int out_size, void* d_ws, size_t ws_size,
                              hipStream_t stream) {
    const float* x     = (const float*)d_in[0];
    const int*   ei    = (const int*)d_in[1];
    const int*   batch = (const int*)d_in[2];
    const float* Wl1   = (const float*)d_in[3];
    const float* bl1   = (const float*)d_in[4];
    const float* Wr1   = (const float*)d_in[5];
    const float* br1   = (const float*)d_in[6];
    const float* att1  = (const float*)d_in[7];
    const float* bias1 = (const float*)d_in[8];
    const float* Wl2   = (const float*)d_in[9];
    const float* bl2   = (const float*)d_in[10];
    const float* Wr2   = (const float*)d_in[11];
    const float* br2   = (const float*)d_in[12];
    const float* att2  = (const float*)d_in[13];
    const float* bias2 = (const float*)d_in[14];
    const float* Wlin  = (const float*)d_in[15];
    const float* blin  = (const float*)d_in[16];
    float* out = (float*)d_out;

    char* w = (char*)d_ws;
    float* bufA = (float*)w;  w += (size_t)N_NODES * D1 * 4;   // xl1 ; later xl2|xr2
    float* bufB = (float*)w;  w += (size_t)N_NODES * D1 * 4;   // xr1 -> h1 ; later h2
    float* e1   = (float*)w;  w += (size_t)ETOT * NHEAD1 * 4;
    float* e2   = (float*)w;  w += (size_t)ETOT * 4;
    int* deg    = (int*)w;    w += (size_t)N_NODES * 4;
    int* row_ptr= (int*)w;    w += (size_t)(N_NODES + 1) * 4;
    int* cursor = (int*)w;    w += (size_t)N_NODES * 4;
    int* csr_src= (int*)w;    w += (size_t)ETOT * 4;
    int* csr_eid= (int*)w;    w += (size_t)ETOT * 4;
    float* pool_sum = (float*)w;  w += (size_t)B_G * C2 * 4;
    float* pool_max = (float*)w;  w += (size_t)B_G * C2 * 4;
    int*   pool_cnt = (int*)w;    w += (size_t)B_G * 4;

    float* xl1 = bufA;
    float* xr1 = bufB;
    float* h1  = bufB;                              // overwrites xr1 (dead after k_att1)
    float* xl2 = bufA;                              // overwrites xl1 (dead after k_agg1)
    float* xr2 = bufA + (size_t)N_NODES * C2;
    float* h2  = bufB;                              // overwrites h1 (dead after k_lin2)

    // init deg
    k_init<<<(N_NODES + 255) / 256, 256, 0, stream>>>(deg);
    // conv1 linear
    k_lin1<<<N_NODES, 256, 0, stream>>>(x, Wl1, bl1, Wr1, br1, xl1, xr1);
    // CSR build (shared by both convs)
    k_deg<<<(ETOT + 255) / 256, 256, 0, stream>>>(ei, deg);
    k_scan<<<1, 1024, 0, stream>>>(deg, row_ptr, cursor);
    k_fill<<<(ETOT + 255) / 256, 256, 0, stream>>>(ei, cursor, csr_src, csr_eid);
    // conv1 attention + aggregation
    k_att1<<<(ETOT * NHEAD1 + 255) / 256, 256, 0, stream>>>(ei, xl1, xr1, att1, e1);
    k_agg1<<<N_NODES, 256, 0, stream>>>(row_ptr, csr_src, csr_eid, e1, xl1, bias1, h1);
    // conv2
    k_lin2<<<N_NODES / LIN2_NB, 256, 0, stream>>>(h1, Wl2, bl2, Wr2, br2, xl2, xr2);
    k_att2<<<(ETOT + 255) / 256, 256, 0, stream>>>(ei, xl2, xr2, att2, e2);
    k_agg2<<<N_NODES, 64, 0, stream>>>(row_ptr, csr_src, csr_eid, e2, xl2, bias2, h2);
    // pooling (atomic-free) + head
    k_pool<<<B_G, 256, 0, stream>>>(h2, batch, pool_sum, pool_max, pool_cnt);
    k_final<<<1, 128, 0, stream>>>(pool_sum, pool_max, pool_cnt, Wlin, blin, out);
}

// Round 13
// 563.606 us; speedup vs baseline: 1.9944x; 1.3176x over previous
//
#include <hip/hip_runtime.h>
#include <math.h>

#define N_NODES 50000
#define E_EDGES 250000
#define ETOT    300000   // E + N self loops
#define B_G     64
#define NHEAD1  4
#define C1      64
#define D1      256      // NHEAD1*C1
#define C2      64
#define NEG     0.2f

__device__ __forceinline__ float leaky(float v){ return v >= 0.f ? v : NEG * v; }
__device__ __forceinline__ float elu_f(float v){ return v > 0.f ? v : expm1f(v); }

// ---------------- init ----------------
__global__ void k_init(int* deg){
    int i = blockIdx.x * 256 + threadIdx.x;
    if (i < N_NODES) deg[i] = 0;
}

// ---------------- conv1 linear (K=5) ----------------
__global__ void k_lin1(const float* __restrict__ x,
                       const float* __restrict__ Wl, const float* __restrict__ bl,
                       const float* __restrict__ Wr, const float* __restrict__ br,
                       float* __restrict__ xl, float* __restrict__ xr){
    int n = blockIdx.x;          // node
    int o = threadIdx.x;         // 0..255
    float x0 = x[n*5+0], x1 = x[n*5+1], x2 = x[n*5+2], x3 = x[n*5+3], x4 = x[n*5+4];
    float vl = bl[o] + x0*Wl[o] + x1*Wl[256+o] + x2*Wl[512+o] + x3*Wl[768+o] + x4*Wl[1024+o];
    float vr = br[o] + x0*Wr[o] + x1*Wr[256+o] + x2*Wr[512+o] + x3*Wr[768+o] + x4*Wr[1024+o];
    int idx = n * D1 + o;
    xl[idx] = vl;
    xr[idx] = vr;
}

// ---------------- CSR build ----------------
__global__ void k_deg(const int* __restrict__ ei, int* __restrict__ deg){
    int e = blockIdx.x * 256 + threadIdx.x;
    if (e >= ETOT) return;
    int dst = (e < E_EDGES) ? ei[E_EDGES + e] : (e - E_EDGES);
    atomicAdd(&deg[dst], 1);
}

__global__ void k_scan(const int* __restrict__ deg, int* __restrict__ row_ptr, int* __restrict__ cursor){
    __shared__ int part[1024];
    int t = threadIdx.x;
    const int CH = (N_NODES + 1023) / 1024;
    int base = t * CH;
    int s = 0;
    for (int k = 0; k < CH; k++){ int i = base + k; if (i < N_NODES) s += deg[i]; }
    part[t] = s;
    __syncthreads();
    for (int off = 1; off < 1024; off <<= 1){
        int v = (t >= off) ? part[t - off] : 0;
        __syncthreads();
        part[t] += v;
        __syncthreads();
    }
    int run = (t == 0) ? 0 : part[t - 1];
    for (int k = 0; k < CH; k++){
        int i = base + k;
        if (i < N_NODES){ row_ptr[i] = run; cursor[i] = run; run += deg[i]; }
    }
    if (t == 1023) row_ptr[N_NODES] = part[1023];
}

__global__ void k_fill(const int* __restrict__ ei, int* __restrict__ cursor,
                       int* __restrict__ csr_src){
    int e = blockIdx.x * 256 + threadIdx.x;
    if (e >= ETOT) return;
    int src, dst;
    if (e < E_EDGES){ src = ei[e]; dst = ei[E_EDGES + e]; }
    else            { src = dst = e - E_EDGES; }
    int pos = atomicAdd(&cursor[dst], 1);
    csr_src[pos] = src;
}

// ---------------- conv1 fused: logits + online softmax + gather + ELU ----------------
// One block (256 thr = 4 waves) per dst node; wave h owns head h.
__global__ void k_conv1(const int* __restrict__ row_ptr, const int* __restrict__ csr_src,
                        const float* __restrict__ xl, const float* __restrict__ xr,
                        const float* __restrict__ att, const float* __restrict__ bias,
                        float* __restrict__ hout){
    int nd = blockIdx.x;
    int t = threadIdx.x;          // channel 0..255 (head = t>>6, lane = t&63)
    int beg = row_ptr[nd], end = row_ptr[nd + 1];
    float xr_v  = xr[(size_t)nd * D1 + t];   // read before any block writes hout[nd]
    float att_v = att[t];                    // att1 is [H1,C1] flat = 256
    float m = -INFINITY, s = 0.f, acc = 0.f;
    for (int k = beg; k < end; k++){
        int src = csr_src[k];
        float xv = xl[(size_t)src * D1 + t];       // 256B coalesced per wave
        float c = leaky(xv + xr_v) * att_v;
        #pragma unroll
        for (int off = 32; off > 0; off >>= 1)     // 64-lane sum -> head logit
            c += __shfl_xor(c, off, 64);
        float mn    = fmaxf(m, c);
        float scale = __expf(m - mn);              // m=-inf first iter -> 0
        float wgt   = __expf(c - mn);
        s   = s * scale + wgt;
        acc = acc * scale + wgt * xv;
        m = mn;
    }
    hout[(size_t)nd * D1 + t] = elu_f(acc / s + bias[t]);
}

// ---------------- conv2 linear (K=256), 16 nodes per block ----------------
#define LIN2_NB 16
__global__ void k_lin2(const float* __restrict__ h1,
                       const float* __restrict__ Wl, const float* __restrict__ bl,
                       const float* __restrict__ Wr, const float* __restrict__ br,
                       float* __restrict__ xl2, float* __restrict__ xr2){
    __shared__ float rows[LIN2_NB * D1];   // 16 KB, same layout as h1 slab
    int base = blockIdx.x * LIN2_NB;       // first node of this block
    int t = threadIdx.x;                   // 0..255
    const float4* src4 = (const float4*)(h1 + (size_t)base * D1);
    float4* dst4 = (float4*)rows;
    for (int i = t; i < LIN2_NB * D1 / 4; i += 256) dst4[i] = src4[i];
    __syncthreads();

    int c     = t & 63;         // output channel
    int which = (t >> 6) & 1;   // 0 = l, 1 = r
    int ng    = t >> 7;         // node parity 0..1
    const float* W = which ? Wr : Wl;
    float bias = which ? br[c] : bl[c];
    float acc[8];
    #pragma unroll
    for (int j = 0; j < 8; j++) acc[j] = bias;

    for (int k = 0; k < D1; k++){
        float w = W[k * 64 + c];
        #pragma unroll
        for (int j = 0; j < 8; j++)
            acc[j] += rows[(ng + j * 2) * D1 + k] * w;   // LDS broadcast per wave
    }
    float* dst = which ? xr2 : xl2;
    #pragma unroll
    for (int j = 0; j < 8; j++){
        int node = base + ng + j * 2;
        dst[(size_t)node * 64 + c] = acc[j];
    }
}

// ---------------- conv2 fused (H=1): one wave per node ----------------
__global__ void k_conv2(const int* __restrict__ row_ptr, const int* __restrict__ csr_src,
                        const float* __restrict__ xl2, const float* __restrict__ xr2,
                        const float* __restrict__ att, const float* __restrict__ bias,
                        float* __restrict__ hout){
    int w    = threadIdx.x >> 6;   // wave 0..3
    int lane = threadIdx.x & 63;   // channel
    int nd = blockIdx.x * 4 + w;
    if (nd >= N_NODES) return;
    int beg = row_ptr[nd], end = row_ptr[nd + 1];
    float xr_v  = xr2[(size_t)nd * C2 + lane];
    float att_v = att[lane];
    float m = -INFINITY, s = 0.f, acc = 0.f;
    for (int k = beg; k < end; k++){
        int src = csr_src[k];
        float xv = xl2[(size_t)src * C2 + lane];
        float c = leaky(xv + xr_v) * att_v;
        #pragma unroll
        for (int off = 32; off > 0; off >>= 1)
            c += __shfl_xor(c, off, 64);
        float mn    = fmaxf(m, c);
        float scale = __expf(m - mn);
        float wgt   = __expf(c - mn);
        s   = s * scale + wgt;
        acc = acc * scale + wgt * xv;
        m = mn;
    }
    hout[(size_t)nd * C2 + lane] = elu_f(acc / s + bias[lane]);
}

// ---------------- pooling: one block per graph, zero atomics ----------------
__device__ __forceinline__ int lower_bound_batch(const int* __restrict__ batch, int val){
    int lo = 0, hi = N_NODES;
    while (lo < hi){ int mid = (lo + hi) >> 1; if (batch[mid] < val) lo = mid + 1; else hi = mid; }
    return lo;
}

__global__ void k_pool(const float* __restrict__ h2, const int* __restrict__ batch,
                       float* __restrict__ pool_sum, float* __restrict__ pool_max,
                       int* __restrict__ pool_cnt){
    __shared__ float ssum[256], smax[256];
    int b = blockIdx.x;            // graph id
    int t = threadIdx.x;           // 0..255
    int lo = lower_bound_batch(batch, b);
    int hi = lower_bound_batch(batch, b + 1);
    int c = t & 63;                // channel
    int j = t >> 6;                // node slice 0..3
    float s = 0.f, mx = -INFINITY;
    for (int nd = lo + j; nd < hi; nd += 4){
        float v = h2[(size_t)nd * C2 + c];
        s += v;
        mx = fmaxf(mx, v);
    }
    ssum[t] = s; smax[t] = mx;
    __syncthreads();
    if (t < 128){ ssum[t] += ssum[t + 128]; smax[t] = fmaxf(smax[t], smax[t + 128]); }
    __syncthreads();
    if (t < 64){
        pool_sum[b * C2 + t] = ssum[t] + ssum[t + 64];
        pool_max[b * C2 + t] = fmaxf(smax[t], smax[t + 64]);
    }
    if (t == 0) pool_cnt[b] = hi - lo;
}

// ---------------- final linear [B,192]@[192,2] ----------------
__global__ void k_final(const float* __restrict__ pool_sum, const float* __restrict__ pool_max,
                        const int* __restrict__ pool_cnt,
                        const float* __restrict__ Wlin, const float* __restrict__ blin,
                        float* __restrict__ out){
    int t = threadIdx.x;
    if (t >= B_G * 2) return;
    int b = t >> 1, o = t & 1;
    float cnt = fmaxf((float)pool_cnt[b], 1.f);
    float acc = blin[o];
    for (int j = 0; j < C2; j++){
        float sm = pool_sum[b * C2 + j];
        float mx = pool_max[b * C2 + j];
        acc += (sm / cnt) * Wlin[j * 2 + o];
        acc += mx * Wlin[(C2 + j) * 2 + o];
        acc += sm * Wlin[(2 * C2 + j) * 2 + o];
    }
    out[b * 2 + o] = acc;
}

extern "C" void kernel_launch(void* const* d_in, const int* in_sizes, int n_in,
                              void* d_out, int out_size, void* d_ws, size_t ws_size,
                              hipStream_t stream) {
    const float* x     = (const float*)d_in[0];
    const int*   ei    = (const int*)d_in[1];
    const int*   batch = (const int*)d_in[2];
    const float* Wl1   = (const float*)d_in[3];
    const float* bl1   = (const float*)d_in[4];
    const float* Wr1   = (const float*)d_in[5];
    const float* br1   = (const float*)d_in[6];
    const float* att1  = (const float*)d_in[7];
    const float* bias1 = (const float*)d_in[8];
    const float* Wl2   = (const float*)d_in[9];
    const float* bl2   = (const float*)d_in[10];
    const float* Wr2   = (const float*)d_in[11];
    const float* br2   = (const float*)d_in[12];
    const float* att2  = (const float*)d_in[13];
    const float* bias2 = (const float*)d_in[14];
    const float* Wlin  = (const float*)d_in[15];
    const float* blin  = (const float*)d_in[16];
    float* out = (float*)d_out;

    char* w = (char*)d_ws;
    float* bufA = (float*)w;  w += (size_t)N_NODES * D1 * 4;   // xl1 ; later xl2|xr2
    float* bufB = (float*)w;  w += (size_t)N_NODES * D1 * 4;   // xr1 -> h1 ; later h2
    int* deg    = (int*)w;    w += (size_t)N_NODES * 4;
    int* row_ptr= (int*)w;    w += (size_t)(N_NODES + 1) * 4;
    int* cursor = (int*)w;    w += (size_t)N_NODES * 4;
    int* csr_src= (int*)w;    w += (size_t)ETOT * 4;
    float* pool_sum = (float*)w;  w += (size_t)B_G * C2 * 4;
    float* pool_max = (float*)w;  w += (size_t)B_G * C2 * 4;
    int*   pool_cnt = (int*)w;    w += (size_t)B_G * 4;

    float* xl1 = bufA;
    float* xr1 = bufB;
    float* h1  = bufB;                              // conv1 writes over xr1 (safe: dst-indexed)
    float* xl2 = bufA;                              // overwrites xl1 (dead after conv1)
    float* xr2 = bufA + (size_t)N_NODES * C2;
    float* h2  = bufB;                              // overwrites h1 (dead after lin2)

    // init deg
    k_init<<<(N_NODES + 255) / 256, 256, 0, stream>>>(deg);
    // conv1 linear
    k_lin1<<<N_NODES, 256, 0, stream>>>(x, Wl1, bl1, Wr1, br1, xl1, xr1);
    // CSR build (shared by both convs)
    k_deg<<<(ETOT + 255) / 256, 256, 0, stream>>>(ei, deg);
    k_scan<<<1, 1024, 0, stream>>>(deg, row_ptr, cursor);
    k_fill<<<(ETOT + 255) / 256, 256, 0, stream>>>(ei, cursor, csr_src);
    // conv1 fused (att + softmax + agg + ELU)
    k_conv1<<<N_NODES, 256, 0, stream>>>(row_ptr, csr_src, xl1, xr1, att1, bias1, h1);
    // conv2
    k_lin2<<<N_NODES / LIN2_NB, 256, 0, stream>>>(h1, Wl2, bl2, Wr2, br2, xl2, xr2);
    k_conv2<<<(N_NODES + 3) / 4, 256, 0, stream>>>(row_ptr, csr_src, xl2, xr2, att2, bias2, h2);
    // pooling (atomic-free) + head
    k_pool<<<B_G, 256, 0, stream>>>(h2, batch, pool_sum, pool_max, pool_cnt);
    k_final<<<1, 128, 0, stream>>>(pool_sum, pool_max, pool_cnt, Wlin, blin, out);
}